// Round 5
// baseline (259.019 us; speedup 1.0000x reference)
//
#include <hip/hip_runtime.h>
#include <math.h>

#define NB  8     // batch
#define DM  192   // D_MODEL
#define DH  192   // D_HALF
#define DI  384   // D_INNER
#define DS  128   // D_STATE
#define DTR 12    // DT_RANK
#define XR  268   // DT_RANK + 2*D_STATE
#define L   1024  // H*W
#define NC  16    // scan chunks
#define CL  64    // chunk length
#define NWX 320   // padded row length for transposed W_xproj
#define LOG2E 1.44269504f

// ---------------------------------------------------------------------------
// Fused weight transpose: W[N][K] row-major -> Wt[K][NW] k-major (zero pad).
__global__ void k_wt_all(const float* __restrict__ Win,
                         const float* __restrict__ Wx,
                         const float* __restrict__ Wout,
                         float* __restrict__ wt_in,
                         float* __restrict__ wt_x,
                         float* __restrict__ wt_out) {
  const int j = blockIdx.x * 256 + threadIdx.x;
  const int k = blockIdx.y;
  const int z = blockIdx.z;
  if (z == 0) {
    if (k < 192 && j < 384) wt_in[(size_t)k * 384 + j] = Win[(size_t)j * 192 + k];
  } else if (z == 1) {
    if (k < 192 && j < NWX) wt_x[(size_t)k * NWX + j] = (j < XR) ? Wx[(size_t)j * 192 + k] : 0.f;
  } else {
    if (k < 384 && j < 192) wt_out[(size_t)k * 192 + j] = Wout[(size_t)j * 384 + k];
  }
}

// ---------------------------------------------------------------------------
// High-density f32 GEMM (round-3 verified): wave-uniform weight strip via
// scalar pipe; A staged in LDS.
template<int K, int N, int NW, int SERP_IN, int OMODE>
__global__ __launch_bounds__(256) void k_gemm(const float* __restrict__ A,
                                              const float* __restrict__ Wt,
                                              float* __restrict__ Out) {
  __shared__ float At[32][64];
  const int lane = threadIdx.x & 63;
  const int wv   = threadIdx.x >> 6;
  const int l    = blockIdx.x * 64 + lane;
  const int n0   = __builtin_amdgcn_readfirstlane(blockIdx.y * 64 + wv * 16);
  const int b    = blockIdx.z;
  int lg = l;
  if (SERP_IN || OMODE == 2) {
    int h = l >> 5, w = l & 31;
    lg = h * 32 + ((h & 1) ? (31 - w) : w);
  }
  const float* Ab = A + (size_t)b * K * L + (SERP_IN ? lg : l);
  float acc[16];
#pragma unroll
  for (int i = 0; i < 16; ++i) acc[i] = 0.f;

  for (int k0 = 0; k0 < K; k0 += 32) {
#pragma unroll
    for (int i = 0; i < 8; ++i) {
      int kr = wv * 8 + i;
      At[kr][lane] = Ab[(size_t)(k0 + kr) * L];
    }
    __syncthreads();
#pragma unroll
    for (int kk = 0; kk < 32; ++kk) {
      float a = At[kk][lane];
      const float* wr = Wt + (size_t)(k0 + kk) * NW + n0;
#pragma unroll
      for (int i = 0; i < 16; ++i) acc[i] = fmaf(wr[i], a, acc[i]);
    }
    __syncthreads();
  }

  if (OMODE == 0) {
    float* o = Out + ((size_t)b * N + n0) * L + l;
#pragma unroll
    for (int i = 0; i < 16; ++i) o[(size_t)i * L] = acc[i];
  } else if (OMODE == 1) {
    float* o = Out + ((size_t)b * L + l) * XR;
#pragma unroll
    for (int i = 0; i < 16; i += 4) {
      if (n0 + i + 4 <= XR)
        *(float4*)(o + n0 + i) = make_float4(acc[i], acc[i + 1], acc[i + 2], acc[i + 3]);
    }
  } else {
    float* o = Out + ((size_t)b * N + n0) * L + lg;
#pragma unroll
    for (int i = 0; i < 16; ++i) o[(size_t)i * L] = acc[i];
  }
}

// ---------------------------------------------------------------------------
// causal depthwise conv (k=4) + SiLU, 4 l per thread (float4).
__global__ void k_conv_silu(const float* __restrict__ xz,
                            const float* __restrict__ cwx,
                            const float* __restrict__ cwz,
                            float* __restrict__ u,
                            float* __restrict__ ycat) {
  int idx = blockIdx.x * blockDim.x + threadIdx.x;
  const int per = NB * DH * (L / 4);
  int part = idx / per;
  int rem  = idx - part * per;
  int l4 = (rem & (L / 4 - 1)) * 4;
  int bd = rem >> 8;           // b*DH + d
  int d  = bd % DH;
  int b  = bd / DH;
  const float* cw = (part ? cwz : cwx) + d * 4;
  float w0 = cw[0], w1 = cw[1], w2 = cw[2], w3 = cw[3];
  const float* src = xz + ((size_t)b * DI + (part ? DH + d : d)) * L;
  float4 cur = *(const float4*)(src + l4);
  float pm3 = 0.f, pm2 = 0.f, pm1 = 0.f;
  if (l4 >= 4) {
    float4 p = *(const float4*)(src + l4 - 4);
    pm3 = p.y; pm2 = p.z; pm1 = p.w;
  }
  float s0 = fmaf(w3, cur.x, fmaf(w2, pm1,   fmaf(w1, pm2,   w0 * pm3)));
  float s1 = fmaf(w3, cur.y, fmaf(w2, cur.x, fmaf(w1, pm1,   w0 * pm2)));
  float s2 = fmaf(w3, cur.z, fmaf(w2, cur.y, fmaf(w1, cur.x, w0 * pm1)));
  float s3 = fmaf(w3, cur.w, fmaf(w2, cur.z, fmaf(w1, cur.y, w0 * cur.x)));
  float4 y;
  y.x = s0 / (1.f + __expf(-s0));
  y.y = s1 / (1.f + __expf(-s1));
  y.z = s2 / (1.f + __expf(-s2));
  y.w = s3 / (1.f + __expf(-s3));
  float* dst = part ? (ycat + ((size_t)b * DI + DH + d) * L + l4)
                    : (u + (size_t)bd * L + l4);
  *(float4*)dst = y;
}

// ---------------------------------------------------------------------------
// delta[b][d][l] = softplus( W_dt . x_dbl + 2*b_dt[d] )  (ref adds b_dt twice)
__global__ void k_delta(const float* __restrict__ xdbl,
                        const float* __restrict__ Wdt,
                        const float* __restrict__ bdt,
                        float* __restrict__ delta) {
  int idx = blockIdx.x * blockDim.x + threadIdx.x;  // (b*DH+d)*L + l
  int l  = idx & (L - 1);
  int bd = idx >> 10;
  int d  = bd % DH;
  int b  = bd / DH;
  const float* xd = xdbl + ((size_t)b * L + l) * XR;
  const float* wd = Wdt + d * DTR;
  float s = 2.f * bdt[d];
#pragma unroll
  for (int r = 0; r < DTR; ++r) s = fmaf(wd[r], xd[r], s);
  float dl = (s > 20.f) ? s : __logf(1.f + __expf(s));
  delta[(size_t)idx] = dl;
}

// ---------------------------------------------------------------------------
// Chunked scan pass 1. Wave carries 4 d-chains (16-lane groups); each lane
// holds 8 consecutive states n = 8j..8j+7 (float4 pairs). The 4 groups load
// the same B lines -> coalesced line sharing. No LDS.
// xdbl layout: row stride XR, B at col 12+n, C at col 140+n.
__global__ void __launch_bounds__(256) k_scan1(const float* __restrict__ xdbl,
                                               const float* __restrict__ delta,
                                               const float* __restrict__ u,
                                               const float* __restrict__ Alog,
                                               float* __restrict__ hpart,
                                               float* __restrict__ apart) {
  const int tid = threadIdx.x;
  const int wv = tid >> 6, g = (tid >> 4) & 3, j = tid & 15;
  const int d = blockIdx.x * 16 + wv * 4 + g;
  const int c = blockIdx.y, b = blockIdx.z;
  const int bd = b * DH + d;
  float a[8];
  {
    const float4* Ap = (const float4*)(Alog + d * DS + 8 * j);
    float4 A0 = Ap[0], A1 = Ap[1];
    a[0] = -__expf(A0.x) * LOG2E; a[1] = -__expf(A0.y) * LOG2E;
    a[2] = -__expf(A0.z) * LOG2E; a[3] = -__expf(A0.w) * LOG2E;
    a[4] = -__expf(A1.x) * LOG2E; a[5] = -__expf(A1.y) * LOG2E;
    a[6] = -__expf(A1.z) * LOG2E; a[7] = -__expf(A1.w) * LOG2E;
  }
  const float* xrow = xdbl + ((size_t)b * L + c * CL) * XR + DTR + 8 * j;
  const float* drow = delta + (size_t)bd * L + c * CL;
  const float* urow = u + (size_t)bd * L + c * CL;
  float h[8]  = {0.f,0.f,0.f,0.f,0.f,0.f,0.f,0.f};
  float ap[8] = {1.f,1.f,1.f,1.f,1.f,1.f,1.f,1.f};
#pragma unroll 4
  for (int t = 0; t < CL; ++t) {
    float4 B0 = *(const float4*)(xrow + (size_t)t * XR);
    float4 B1 = *(const float4*)(xrow + (size_t)t * XR + 4);
    float Bv[8] = {B0.x,B0.y,B0.z,B0.w,B1.x,B1.y,B1.z,B1.w};
    float dt = drow[t], ut = urow[t];
    float du = dt * ut;
#pragma unroll
    for (int s = 0; s < 8; ++s) {
      float e = __builtin_amdgcn_exp2f(dt * a[s]);
      h[s] = fmaf(e, h[s], du * Bv[s]);
      ap[s] *= e;
    }
  }
  float* hp  = hpart + ((size_t)bd * NC + c) * 128 + 8 * j;
  float* app = apart + ((size_t)bd * NC + c) * 128 + 8 * j;
  *(float4*)(hp)      = make_float4(h[0], h[1], h[2], h[3]);
  *(float4*)(hp + 4)  = make_float4(h[4], h[5], h[6], h[7]);
  *(float4*)(app)     = make_float4(ap[0], ap[1], ap[2], ap[3]);
  *(float4*)(app + 4) = make_float4(ap[4], ap[5], ap[6], ap[7]);
}

// ---------------------------------------------------------------------------
// pass 2: serial combine; overwrites hpart with true incoming state per chunk.
// (layout: state n of (bd,c) at hpart[(bd*NC+c)*128 + n])
__global__ void __launch_bounds__(64) k_scan2(float* __restrict__ hpart,
                                              const float* __restrict__ apart) {
  const int bd   = blockIdx.x;
  const int lane = threadIdx.x;
  float H1 = 0.f, H2 = 0.f;
  size_t base = (size_t)bd * (NC * 128) + lane;
  for (int c = 0; c < NC; ++c) {
    size_t o = base + c * 128;
    float hp1 = hpart[o], hp2 = hpart[o + 64];
    float ap1 = apart[o], ap2 = apart[o + 64];
    hpart[o] = H1; hpart[o + 64] = H2;
    H1 = fmaf(ap1, H1, hp1);
    H2 = fmaf(ap2, H2, hp2);
  }
}

// ---------------------------------------------------------------------------
// pass 3: recompute from true h_in, emit y. 4-chain wave structure; the
// 16-step transpose-reduce goes through LDS with EXPLICIT barriers on both
// sides (cross-lane LDS communication without barriers is a compiler-level
// data race -- suspected cause of the round-4 failure).
__global__ void __launch_bounds__(256) k_scan3(const float* __restrict__ xdbl,
                                               const float* __restrict__ delta,
                                               const float* __restrict__ u,
                                               const float* __restrict__ Alog,
                                               const float* __restrict__ Dp,
                                               const float* __restrict__ hin,
                                               float* __restrict__ ycat) {
  __shared__ float pbuf[4][4][16][17];
  const int tid = threadIdx.x;
  const int wv = tid >> 6, g = (tid >> 4) & 3, j = tid & 15;
  const int d = blockIdx.x * 16 + wv * 4 + g;
  const int c = blockIdx.y, b = blockIdx.z;
  const int bd = b * DH + d;
  float a[8];
  {
    const float4* Ap = (const float4*)(Alog + d * DS + 8 * j);
    float4 A0 = Ap[0], A1 = Ap[1];
    a[0] = -__expf(A0.x) * LOG2E; a[1] = -__expf(A0.y) * LOG2E;
    a[2] = -__expf(A0.z) * LOG2E; a[3] = -__expf(A0.w) * LOG2E;
    a[4] = -__expf(A1.x) * LOG2E; a[5] = -__expf(A1.y) * LOG2E;
    a[6] = -__expf(A1.z) * LOG2E; a[7] = -__expf(A1.w) * LOG2E;
  }
  const float Dd = Dp[d];
  const float* xrow = xdbl + ((size_t)b * L + c * CL) * XR + DTR + 8 * j;
  const float* drow = delta + (size_t)bd * L + c * CL;
  const float* urow = u + (size_t)bd * L + c * CL;
  float* yrow = ycat + ((size_t)b * DI + d) * L + c * CL;
  const float* hp = hin + ((size_t)bd * NC + c) * 128 + 8 * j;
  float4 H0 = *(const float4*)(hp), H1 = *(const float4*)(hp + 4);
  float h[8] = {H0.x,H0.y,H0.z,H0.w,H1.x,H1.y,H1.z,H1.w};

  for (int t16 = 0; t16 < 4; ++t16) {
#pragma unroll
    for (int i = 0; i < 16; ++i) {
      int t = t16 * 16 + i;
      float4 B0 = *(const float4*)(xrow + (size_t)t * XR);
      float4 B1 = *(const float4*)(xrow + (size_t)t * XR + 4);
      float4 C0 = *(const float4*)(xrow + (size_t)t * XR + 128);
      float4 C1 = *(const float4*)(xrow + (size_t)t * XR + 132);
      float Bv[8] = {B0.x,B0.y,B0.z,B0.w,B1.x,B1.y,B1.z,B1.w};
      float Cv[8] = {C0.x,C0.y,C0.z,C0.w,C1.x,C1.y,C1.z,C1.w};
      float dt = drow[t], ut = urow[t];
      float du = dt * ut;
      float p = 0.f;
#pragma unroll
      for (int s = 0; s < 8; ++s) {
        float e = __builtin_amdgcn_exp2f(dt * a[s]);
        h[s] = fmaf(e, h[s], du * Bv[s]);
        p = fmaf(h[s], Cv[s], p);
      }
      pbuf[wv][g][i][j] = p;
    }
    __syncthreads();                    // writes visible before transpose read
    float s = 0.f;
#pragma unroll
    for (int i2 = 0; i2 < 16; ++i2) s += pbuf[wv][g][j][i2];
    float uo = urow[t16 * 16 + j];
    yrow[t16 * 16 + j] = fmaf(Dd, uo, s);
    __syncthreads();                    // reads done before next-iter writes
  }
}

// ---------------------------------------------------------------------------
// fallback serial scan (round-3 verified), used only if ws too small.
__global__ void __launch_bounds__(64) k_scan(const float* __restrict__ xdbl,
                                             const float* __restrict__ delta,
                                             const float* __restrict__ u,
                                             const float* __restrict__ Alog,
                                             const float* __restrict__ Dp,
                                             float* __restrict__ ycat) {
  const int bd   = blockIdx.x;
  const int b    = bd / DH;
  const int d    = bd % DH;
  const int lane = threadIdx.x;
  const float a1 = -__expf(Alog[d * DS + lane]);
  const float a2 = -__expf(Alog[d * DS + 64 + lane]);
  const float* xrow = xdbl + (size_t)b * L * XR;
  const float* drow = delta + (size_t)bd * L;
  const float* urow = u + (size_t)bd * L;
  const float Dd = Dp[d];
  float* yrow = ycat + ((size_t)b * DI + d) * L;
  float h1 = 0.f, h2 = 0.f;
  for (int t = 0; t < L; ++t) {
    const float* xd = xrow + (size_t)t * XR;
    float Bv1 = xd[DTR + lane];
    float Bv2 = xd[DTR + 64 + lane];
    float Cv1 = xd[DTR + DS + lane];
    float Cv2 = xd[DTR + DS + 64 + lane];
    float dt = drow[t];
    float ut = urow[t];
    float du = dt * ut;
    h1 = fmaf(__expf(dt * a1), h1, du * Bv1);
    h2 = fmaf(__expf(dt * a2), h2, du * Bv2);
    float p = fmaf(h2, Cv2, h1 * Cv1);
#pragma unroll
    for (int m = 32; m; m >>= 1) p += __shfl_xor(p, m, 64);
    if (lane == 0) yrow[t] = fmaf(Dd, ut, p);
  }
}

// ---------------------------------------------------------------------------
extern "C" void kernel_launch(void* const* d_in, const int* in_sizes, int n_in,
                              void* d_out, int out_size, void* d_ws, size_t ws_size,
                              hipStream_t stream) {
  const float* hid  = (const float*)d_in[0];
  const float* Win  = (const float*)d_in[1];
  const float* cwx  = (const float*)d_in[2];
  const float* cwz  = (const float*)d_in[3];
  const float* Wx   = (const float*)d_in[4];
  const float* Wdt  = (const float*)d_in[5];
  const float* bdt  = (const float*)d_in[6];
  const float* Alog = (const float*)d_in[7];
  const float* Dp   = (const float*)d_in[8];
  const float* Wout = (const float*)d_in[9];
  float* out = (float*)d_out;

  float* ws    = (float*)d_ws;
  float* xz    = ws;                          // NB*DI*L   = 3,145,728
  float* u     = xz   + (size_t)NB * DI * L;  // NB*DH*L   = 1,572,864
  float* ycat  = u    + (size_t)NB * DH * L;  // NB*DI*L   = 3,145,728
  float* xdbl  = ycat + (size_t)NB * DI * L;  // NB*L*XR   = 2,195,456
  float* delta = xdbl + (size_t)NB * L * XR;  // NB*DH*L   = 1,572,864
  float* apart = delta + (size_t)NB * DH * L; // NB*DH*NC*128 = 3,145,728
  float* wt_in = apart + (size_t)NB * DH * NC * 128;  // 192*384 = 73,728
  float* wt_x  = wt_in + (size_t)192 * 384;           // 192*320 = 61,440
  float* wt_out= wt_x  + (size_t)192 * NWX;           // 384*192 = 73,728
  float* hpart = xz;                          // aliases xz (dead after conv)

  const size_t need = ((size_t)NB * DI * L * 2 + (size_t)NB * DH * L * 2 +
                       (size_t)NB * L * XR + (size_t)NB * DH * NC * 128 +
                       (size_t)192 * 384 + (size_t)192 * NWX + (size_t)384 * 192) * 4;

  k_wt_all<<<dim3(2, 384, 3), dim3(256), 0, stream>>>(Win, Wx, Wout, wt_in, wt_x, wt_out);

  k_gemm<192, 384, 384, 1, 0><<<dim3(16, 6, NB), dim3(256), 0, stream>>>(hid, wt_in, xz);
  k_conv_silu<<<dim3(2 * NB * DH * (L / 4) / 256), dim3(256), 0, stream>>>(xz, cwx, cwz, u, ycat);
  k_gemm<192, XR, NWX, 0, 1><<<dim3(16, 5, NB), dim3(256), 0, stream>>>(u, wt_x, xdbl);
  k_delta<<<dim3(NB * DH * L / 256), dim3(256), 0, stream>>>(xdbl, Wdt, bdt, delta);

  if (ws_size >= need) {
    k_scan1<<<dim3(DH / 16, NC, NB), dim3(256), 0, stream>>>(xdbl, delta, u, Alog, hpart, apart);
    k_scan2<<<dim3(NB * DH), dim3(64), 0, stream>>>(hpart, apart);
    k_scan3<<<dim3(DH / 16, NC, NB), dim3(256), 0, stream>>>(xdbl, delta, u, Alog, Dp, hpart, ycat);
  } else {
    k_scan<<<dim3(NB * DH), dim3(64), 0, stream>>>(xdbl, delta, u, Alog, Dp, ycat);
  }

  k_gemm<384, 192, 192, 0, 2><<<dim3(16, 3, NB), dim3(256), 0, stream>>>(ycat, wt_out, out);
}

// Round 6
// 254.122 us; speedup vs baseline: 1.0193x; 1.0193x over previous
//
#include <hip/hip_runtime.h>
#include <math.h>

#define NB  8     // batch
#define DM  192   // D_MODEL
#define DH  192   // D_HALF
#define DI  384   // D_INNER
#define DS  128   // D_STATE
#define DTR 12    // DT_RANK
#define XR  268   // DT_RANK + 2*D_STATE
#define L   1024  // H*W
#define NC  16    // scan chunks
#define CL  64    // chunk length
#define NWX 320   // padded row length for transposed W_xproj
#define LOG2E 1.44269504f

// ---------------------------------------------------------------------------
// Fused weight transpose: W[N][K] row-major -> Wt[K][NW] k-major (zero pad).
__global__ void k_wt_all(const float* __restrict__ Win,
                         const float* __restrict__ Wx,
                         const float* __restrict__ Wout,
                         float* __restrict__ wt_in,
                         float* __restrict__ wt_x,
                         float* __restrict__ wt_out) {
  const int j = blockIdx.x * 256 + threadIdx.x;
  const int k = blockIdx.y;
  const int z = blockIdx.z;
  if (z == 0) {
    if (k < 192 && j < 384) wt_in[(size_t)k * 384 + j] = Win[(size_t)j * 192 + k];
  } else if (z == 1) {
    if (k < 192 && j < NWX) wt_x[(size_t)k * NWX + j] = (j < XR) ? Wx[(size_t)j * 192 + k] : 0.f;
  } else {
    if (k < 384 && j < 192) wt_out[(size_t)k * 192 + j] = Wout[(size_t)j * 384 + k];
  }
}

// ---------------------------------------------------------------------------
// High-density f32 GEMM: wave-uniform weight strip via scalar pipe; A staged
// in LDS. OMODE 0: Out[n][l]; 1: Out[l][n] (x_dbl); 2: Out[n][serp(l)].
// DODT (with OMODE 1): the n0==0 wave additionally computes
// delta[b][d][l] = softplus(sum_r Wdt[d][r]*acc[r] + 2*bdt[d]) for all d
// (acc[0..11] ARE x_dbl[l][0..11]); replaces the separate k_delta kernel.
template<int K, int N, int NW, int SERP_IN, int OMODE, int DODT>
__global__ __launch_bounds__(256) void k_gemm(const float* __restrict__ A,
                                              const float* __restrict__ Wt,
                                              float* __restrict__ Out,
                                              const float* __restrict__ Wdt,
                                              const float* __restrict__ bdt,
                                              float* __restrict__ dlt) {
  __shared__ float At[32][64];
  const int lane = threadIdx.x & 63;
  const int wv   = threadIdx.x >> 6;
  const int l    = blockIdx.x * 64 + lane;
  const int n0   = __builtin_amdgcn_readfirstlane(blockIdx.y * 64 + wv * 16);
  const int b    = blockIdx.z;
  int lg = l;
  if (SERP_IN || OMODE == 2) {
    int h = l >> 5, w = l & 31;
    lg = h * 32 + ((h & 1) ? (31 - w) : w);
  }
  const float* Ab = A + (size_t)b * K * L + (SERP_IN ? lg : l);
  float acc[16];
#pragma unroll
  for (int i = 0; i < 16; ++i) acc[i] = 0.f;

  for (int k0 = 0; k0 < K; k0 += 32) {
#pragma unroll
    for (int i = 0; i < 8; ++i) {
      int kr = wv * 8 + i;
      At[kr][lane] = Ab[(size_t)(k0 + kr) * L];
    }
    __syncthreads();
#pragma unroll
    for (int kk = 0; kk < 32; ++kk) {
      float a = At[kk][lane];
      const float* wr = Wt + (size_t)(k0 + kk) * NW + n0;
#pragma unroll
      for (int i = 0; i < 16; ++i) acc[i] = fmaf(wr[i], a, acc[i]);
    }
    __syncthreads();
  }

  if (OMODE == 0) {
    float* o = Out + ((size_t)b * N + n0) * L + l;
#pragma unroll
    for (int i = 0; i < 16; ++i) o[(size_t)i * L] = acc[i];
  } else if (OMODE == 1) {
    float* o = Out + ((size_t)b * L + l) * XR;
#pragma unroll
    for (int i = 0; i < 16; i += 4) {
      if (n0 + i + 4 <= XR)
        *(float4*)(o + n0 + i) = make_float4(acc[i], acc[i + 1], acc[i + 2], acc[i + 3]);
    }
    if (DODT && n0 == 0) {
      // delta for all d from in-register acc[0..11] (scalar-pipe Wdt/bdt)
      for (int d = 0; d < DH; ++d) {
        const float* wd = Wdt + d * DTR;
        float s = 2.f * bdt[d];
#pragma unroll
        for (int r = 0; r < DTR; ++r) s = fmaf(wd[r], acc[r], s);
        float v = (s > 20.f) ? s : __logf(1.f + __expf(s));
        dlt[((size_t)b * DH + d) * L + l] = v;
      }
    }
  } else {
    float* o = Out + ((size_t)b * N + n0) * L + lg;
#pragma unroll
    for (int i = 0; i < 16; ++i) o[(size_t)i * L] = acc[i];
  }
}

// ---------------------------------------------------------------------------
// causal depthwise conv (k=4) + SiLU, 4 l per thread (float4).
__global__ void k_conv_silu(const float* __restrict__ xz,
                            const float* __restrict__ cwx,
                            const float* __restrict__ cwz,
                            float* __restrict__ u,
                            float* __restrict__ ycat) {
  int idx = blockIdx.x * blockDim.x + threadIdx.x;
  const int per = NB * DH * (L / 4);
  int part = idx / per;
  int rem  = idx - part * per;
  int l4 = (rem & (L / 4 - 1)) * 4;
  int bd = rem >> 8;           // b*DH + d
  int d  = bd % DH;
  int b  = bd / DH;
  const float* cw = (part ? cwz : cwx) + d * 4;
  float w0 = cw[0], w1 = cw[1], w2 = cw[2], w3 = cw[3];
  const float* src = xz + ((size_t)b * DI + (part ? DH + d : d)) * L;
  float4 cur = *(const float4*)(src + l4);
  float pm3 = 0.f, pm2 = 0.f, pm1 = 0.f;
  if (l4 >= 4) {
    float4 p = *(const float4*)(src + l4 - 4);
    pm3 = p.y; pm2 = p.z; pm1 = p.w;
  }
  float s0 = fmaf(w3, cur.x, fmaf(w2, pm1,   fmaf(w1, pm2,   w0 * pm3)));
  float s1 = fmaf(w3, cur.y, fmaf(w2, cur.x, fmaf(w1, pm1,   w0 * pm2)));
  float s2 = fmaf(w3, cur.z, fmaf(w2, cur.y, fmaf(w1, cur.x, w0 * pm1)));
  float s3 = fmaf(w3, cur.w, fmaf(w2, cur.z, fmaf(w1, cur.y, w0 * cur.x)));
  float4 y;
  y.x = s0 / (1.f + __expf(-s0));
  y.y = s1 / (1.f + __expf(-s1));
  y.z = s2 / (1.f + __expf(-s2));
  y.w = s3 / (1.f + __expf(-s3));
  float* dst = part ? (ycat + ((size_t)b * DI + DH + d) * L + l4)
                    : (u + (size_t)bd * L + l4);
  *(float4*)dst = y;
}

// ---------------------------------------------------------------------------
// Chunked scan pass 1 (round-5 verified): wave carries 4 d-chains; lane holds
// 8 consecutive states. No LDS.
__global__ void __launch_bounds__(256) k_scan1(const float* __restrict__ xdbl,
                                               const float* __restrict__ delta,
                                               const float* __restrict__ u,
                                               const float* __restrict__ Alog,
                                               float* __restrict__ hpart,
                                               float* __restrict__ apart) {
  const int tid = threadIdx.x;
  const int wv = tid >> 6, g = (tid >> 4) & 3, j = tid & 15;
  const int d = blockIdx.x * 16 + wv * 4 + g;
  const int c = blockIdx.y, b = blockIdx.z;
  const int bd = b * DH + d;
  float a[8];
  {
    const float4* Ap = (const float4*)(Alog + d * DS + 8 * j);
    float4 A0 = Ap[0], A1 = Ap[1];
    a[0] = -__expf(A0.x) * LOG2E; a[1] = -__expf(A0.y) * LOG2E;
    a[2] = -__expf(A0.z) * LOG2E; a[3] = -__expf(A0.w) * LOG2E;
    a[4] = -__expf(A1.x) * LOG2E; a[5] = -__expf(A1.y) * LOG2E;
    a[6] = -__expf(A1.z) * LOG2E; a[7] = -__expf(A1.w) * LOG2E;
  }
  const float* xrow = xdbl + ((size_t)b * L + c * CL) * XR + DTR + 8 * j;
  const float* drow = delta + (size_t)bd * L + c * CL;
  const float* urow = u + (size_t)bd * L + c * CL;
  float h[8]  = {0.f,0.f,0.f,0.f,0.f,0.f,0.f,0.f};
  float ap[8] = {1.f,1.f,1.f,1.f,1.f,1.f,1.f,1.f};
#pragma unroll 4
  for (int t = 0; t < CL; ++t) {
    float4 B0 = *(const float4*)(xrow + (size_t)t * XR);
    float4 B1 = *(const float4*)(xrow + (size_t)t * XR + 4);
    float Bv[8] = {B0.x,B0.y,B0.z,B0.w,B1.x,B1.y,B1.z,B1.w};
    float dt = drow[t], ut = urow[t];
    float du = dt * ut;
#pragma unroll
    for (int s = 0; s < 8; ++s) {
      float e = __builtin_amdgcn_exp2f(dt * a[s]);
      h[s] = fmaf(e, h[s], du * Bv[s]);
      ap[s] *= e;
    }
  }
  float* hp  = hpart + ((size_t)bd * NC + c) * 128 + 8 * j;
  float* app = apart + ((size_t)bd * NC + c) * 128 + 8 * j;
  *(float4*)(hp)      = make_float4(h[0], h[1], h[2], h[3]);
  *(float4*)(hp + 4)  = make_float4(h[4], h[5], h[6], h[7]);
  *(float4*)(app)     = make_float4(ap[0], ap[1], ap[2], ap[3]);
  *(float4*)(app + 4) = make_float4(ap[4], ap[5], ap[6], ap[7]);
}

// ---------------------------------------------------------------------------
// pass 2: serial combine; overwrites hpart with true incoming state per chunk.
__global__ void __launch_bounds__(64) k_scan2(float* __restrict__ hpart,
                                              const float* __restrict__ apart) {
  const int bd   = blockIdx.x;
  const int lane = threadIdx.x;
  float H1 = 0.f, H2 = 0.f;
  size_t base = (size_t)bd * (NC * 128) + lane;
  for (int c = 0; c < NC; ++c) {
    size_t o = base + c * 128;
    float hp1 = hpart[o], hp2 = hpart[o + 64];
    float ap1 = apart[o], ap2 = apart[o + 64];
    hpart[o] = H1; hpart[o + 64] = H2;
    H1 = fmaf(ap1, H1, hp1);
    H2 = fmaf(ap2, H2, hp2);
  }
}

// ---------------------------------------------------------------------------
// pass 3: ONE chain per wave (round-3 structure: 24576 waves for TLP),
// float2 state-pairing (lane owns states 2i,2i+1), dt/du preloaded per chunk
// and shfl-broadcast per step, barriered LDS transpose-reduce per 16 steps.
__global__ void __launch_bounds__(256) k_scan3(const float* __restrict__ xdbl,
                                               const float* __restrict__ delta,
                                               const float* __restrict__ u,
                                               const float* __restrict__ Alog,
                                               const float* __restrict__ Dp,
                                               const float* __restrict__ hin,
                                               float* __restrict__ ycat) {
  __shared__ float pbuf[4][16][65];
  const int lane = threadIdx.x & 63;
  const int wv   = threadIdx.x >> 6;
  const int d    = blockIdx.x * 4 + wv;
  const int c    = blockIdx.y, b = blockIdx.z;
  const int bd   = b * DH + d;
  float2 Af = *(const float2*)(Alog + d * DS + 2 * lane);
  const float a0 = -__expf(Af.x) * LOG2E;
  const float a1 = -__expf(Af.y) * LOG2E;
  const float Dd = Dp[d];
  const float* xrow = xdbl + ((size_t)b * L + c * CL) * XR + DTR + 2 * lane;
  const float* drow = delta + (size_t)bd * L + c * CL;
  const float* urow = u + (size_t)bd * L + c * CL;
  float* yrow = ycat + ((size_t)b * DI + d) * L + c * CL;
  const float* hp = hin + ((size_t)bd * NC + c) * 128 + 2 * lane;
  float2 H = *(const float2*)hp;
  float h0 = H.x, h1 = H.y;
  // lane t holds dt[t], dt[t]*u[t] for the whole chunk (CL==64)
  float dtv = drow[lane];
  float duv = dtv * urow[lane];
  const int tl = lane & 15, pp = lane >> 4;
  for (int t16 = 0; t16 < 4; ++t16) {
#pragma unroll
    for (int i = 0; i < 16; ++i) {
      int t = t16 * 16 + i;
      float2 Bv = *(const float2*)(xrow + (size_t)t * XR);
      float2 Cv = *(const float2*)(xrow + (size_t)t * XR + DS);
      float dt = __shfl(dtv, t, 64);
      float du = __shfl(duv, t, 64);
      float e0 = __builtin_amdgcn_exp2f(dt * a0);
      float e1 = __builtin_amdgcn_exp2f(dt * a1);
      h0 = fmaf(e0, h0, du * Bv.x);
      h1 = fmaf(e1, h1, du * Bv.y);
      pbuf[wv][i][lane] = fmaf(h1, Cv.y, h0 * Cv.x);
    }
    __syncthreads();                    // writes visible before transpose read
    float s = 0.f;
#pragma unroll
    for (int i2 = 0; i2 < 16; ++i2) s += pbuf[wv][tl][pp * 16 + i2];
    s += __shfl_xor(s, 16, 64);
    s += __shfl_xor(s, 32, 64);
    if (lane < 16) {
      float uo = urow[t16 * 16 + tl];
      yrow[t16 * 16 + tl] = fmaf(Dd, uo, s);
    }
    __syncthreads();                    // reads done before next-iter writes
  }
}

// ---------------------------------------------------------------------------
// fallback serial scan, used only if ws too small.
__global__ void __launch_bounds__(64) k_scan(const float* __restrict__ xdbl,
                                             const float* __restrict__ delta,
                                             const float* __restrict__ u,
                                             const float* __restrict__ Alog,
                                             const float* __restrict__ Dp,
                                             float* __restrict__ ycat) {
  const int bd   = blockIdx.x;
  const int b    = bd / DH;
  const int d    = bd % DH;
  const int lane = threadIdx.x;
  const float a1 = -__expf(Alog[d * DS + lane]);
  const float a2 = -__expf(Alog[d * DS + 64 + lane]);
  const float* xrow = xdbl + (size_t)b * L * XR;
  const float* drow = delta + (size_t)bd * L;
  const float* urow = u + (size_t)bd * L;
  const float Dd = Dp[d];
  float* yrow = ycat + ((size_t)b * DI + d) * L;
  float h1 = 0.f, h2 = 0.f;
  for (int t = 0; t < L; ++t) {
    const float* xd = xrow + (size_t)t * XR;
    float Bv1 = xd[DTR + lane];
    float Bv2 = xd[DTR + 64 + lane];
    float Cv1 = xd[DTR + DS + lane];
    float Cv2 = xd[DTR + DS + 64 + lane];
    float dt = drow[t];
    float ut = urow[t];
    float du = dt * ut;
    h1 = fmaf(__expf(dt * a1), h1, du * Bv1);
    h2 = fmaf(__expf(dt * a2), h2, du * Bv2);
    float p = fmaf(h2, Cv2, h1 * Cv1);
#pragma unroll
    for (int m = 32; m; m >>= 1) p += __shfl_xor(p, m, 64);
    if (lane == 0) yrow[t] = fmaf(Dd, ut, p);
  }
}

// ---------------------------------------------------------------------------
extern "C" void kernel_launch(void* const* d_in, const int* in_sizes, int n_in,
                              void* d_out, int out_size, void* d_ws, size_t ws_size,
                              hipStream_t stream) {
  const float* hid  = (const float*)d_in[0];
  const float* Win  = (const float*)d_in[1];
  const float* cwx  = (const float*)d_in[2];
  const float* cwz  = (const float*)d_in[3];
  const float* Wx   = (const float*)d_in[4];
  const float* Wdt  = (const float*)d_in[5];
  const float* bdt  = (const float*)d_in[6];
  const float* Alog = (const float*)d_in[7];
  const float* Dp   = (const float*)d_in[8];
  const float* Wout = (const float*)d_in[9];
  float* out = (float*)d_out;

  float* ws    = (float*)d_ws;
  float* xz    = ws;                          // NB*DI*L   = 3,145,728
  float* u     = xz   + (size_t)NB * DI * L;  // NB*DH*L   = 1,572,864
  float* ycat  = u    + (size_t)NB * DH * L;  // NB*DI*L   = 3,145,728
  float* xdbl  = ycat + (size_t)NB * DI * L;  // NB*L*XR   = 2,195,456
  float* delta = xdbl + (size_t)NB * L * XR;  // NB*DH*L   = 1,572,864
  float* apart = delta + (size_t)NB * DH * L; // NB*DH*NC*128 = 3,145,728
  float* wt_in = apart + (size_t)NB * DH * NC * 128;  // 192*384 = 73,728
  float* wt_x  = wt_in + (size_t)192 * 384;           // 192*320 = 61,440
  float* wt_out= wt_x  + (size_t)192 * NWX;           // 384*192 = 73,728
  float* hpart = xz;                          // aliases xz (dead after conv)

  const size_t need = ((size_t)NB * DI * L * 2 + (size_t)NB * DH * L * 2 +
                       (size_t)NB * L * XR + (size_t)NB * DH * NC * 128 +
                       (size_t)192 * 384 + (size_t)192 * NWX + (size_t)384 * 192) * 4;

  k_wt_all<<<dim3(2, 384, 3), dim3(256), 0, stream>>>(Win, Wx, Wout, wt_in, wt_x, wt_out);

  k_gemm<192, 384, 384, 1, 0, 0><<<dim3(16, 6, NB), dim3(256), 0, stream>>>(
      hid, wt_in, xz, nullptr, nullptr, nullptr);
  k_conv_silu<<<dim3(2 * NB * DH * (L / 4) / 256), dim3(256), 0, stream>>>(xz, cwx, cwz, u, ycat);
  // xproj GEMM + fused delta epilogue (replaces k_delta)
  k_gemm<192, XR, NWX, 0, 1, 1><<<dim3(16, 5, NB), dim3(256), 0, stream>>>(
      u, wt_x, xdbl, Wdt, bdt, delta);

  if (ws_size >= need) {
    k_scan1<<<dim3(DH / 16, NC, NB), dim3(256), 0, stream>>>(xdbl, delta, u, Alog, hpart, apart);
    k_scan2<<<dim3(NB * DH), dim3(64), 0, stream>>>(hpart, apart);
    k_scan3<<<dim3(DH / 4, NC, NB), dim3(256), 0, stream>>>(xdbl, delta, u, Alog, Dp, hpart, ycat);
  } else {
    k_scan<<<dim3(NB * DH), dim3(64), 0, stream>>>(xdbl, delta, u, Alog, Dp, ycat);
  }

  k_gemm<384, 192, 192, 0, 2, 0><<<dim3(16, 3, NB), dim3(256), 0, stream>>>(
      ycat, wt_out, out, nullptr, nullptr, nullptr);
}

// Round 7
// 211.439 us; speedup vs baseline: 1.2250x; 1.2019x over previous
//
#include <hip/hip_runtime.h>
#include <math.h>

#define NB  8     // batch
#define DM  192   // D_MODEL
#define DH  192   // D_HALF
#define DI  384   // D_INNER
#define DS  128   // D_STATE
#define DTR 12    // DT_RANK
#define XR  268   // DT_RANK + 2*D_STATE
#define L   1024  // H*W
#define NC  16    // scan chunks
#define CL  64    // chunk length
#define NWX 320   // padded row length for transposed W_xproj
#define LOG2E 1.44269504f

// Wave-level LDS fence: DS ops from one wave complete in order; we only need
// (1) all issued LDS ops complete (lgkmcnt 0), (2) compiler must not reorder
// LDS accesses across this point. No vmcnt drain, no cross-wave coupling.
__device__ __forceinline__ void wave_lds_sync() {
  __builtin_amdgcn_wave_barrier();
  asm volatile("s_waitcnt lgkmcnt(0)" ::: "memory");
  __builtin_amdgcn_sched_barrier(0);
}

// ---------------------------------------------------------------------------
// Fused weight transpose: W[N][K] row-major -> Wt[K][NW] k-major (zero pad).
__global__ void k_wt_all(const float* __restrict__ Win,
                         const float* __restrict__ Wx,
                         const float* __restrict__ Wout,
                         float* __restrict__ wt_in,
                         float* __restrict__ wt_x,
                         float* __restrict__ wt_out) {
  const int j = blockIdx.x * 256 + threadIdx.x;
  const int k = blockIdx.y;
  const int z = blockIdx.z;
  if (z == 0) {
    if (k < 192 && j < 384) wt_in[(size_t)k * 384 + j] = Win[(size_t)j * 192 + k];
  } else if (z == 1) {
    if (k < 192 && j < NWX) wt_x[(size_t)k * NWX + j] = (j < XR) ? Wx[(size_t)j * 192 + k] : 0.f;
  } else {
    if (k < 384 && j < 192) wt_out[(size_t)k * 192 + j] = Wout[(size_t)j * 384 + k];
  }
}

// ---------------------------------------------------------------------------
// High-density f32 GEMM: wave-uniform weight strip via scalar pipe; A staged
// in LDS. OMODE 0: Out[n][l]; 1: Out[l][n] (x_dbl); 2: Out[n][serp(l)].
// DODT (with OMODE 1): the n0==0 wave additionally computes
// delta[b][d][l] = softplus(sum_r Wdt[d][r]*acc[r] + 2*bdt[d]) for all d.
template<int K, int N, int NW, int SERP_IN, int OMODE, int DODT>
__global__ __launch_bounds__(256) void k_gemm(const float* __restrict__ A,
                                              const float* __restrict__ Wt,
                                              float* __restrict__ Out,
                                              const float* __restrict__ Wdt,
                                              const float* __restrict__ bdt,
                                              float* __restrict__ dlt) {
  __shared__ float At[32][64];
  const int lane = threadIdx.x & 63;
  const int wv   = threadIdx.x >> 6;
  const int l    = blockIdx.x * 64 + lane;
  const int n0   = __builtin_amdgcn_readfirstlane(blockIdx.y * 64 + wv * 16);
  const int b    = blockIdx.z;
  int lg = l;
  if (SERP_IN || OMODE == 2) {
    int h = l >> 5, w = l & 31;
    lg = h * 32 + ((h & 1) ? (31 - w) : w);
  }
  const float* Ab = A + (size_t)b * K * L + (SERP_IN ? lg : l);
  float acc[16];
#pragma unroll
  for (int i = 0; i < 16; ++i) acc[i] = 0.f;

  for (int k0 = 0; k0 < K; k0 += 32) {
#pragma unroll
    for (int i = 0; i < 8; ++i) {
      int kr = wv * 8 + i;
      At[kr][lane] = Ab[(size_t)(k0 + kr) * L];
    }
    __syncthreads();
#pragma unroll
    for (int kk = 0; kk < 32; ++kk) {
      float a = At[kk][lane];
      const float* wr = Wt + (size_t)(k0 + kk) * NW + n0;
#pragma unroll
      for (int i = 0; i < 16; ++i) acc[i] = fmaf(wr[i], a, acc[i]);
    }
    __syncthreads();
  }

  if (OMODE == 0) {
    float* o = Out + ((size_t)b * N + n0) * L + l;
#pragma unroll
    for (int i = 0; i < 16; ++i) o[(size_t)i * L] = acc[i];
  } else if (OMODE == 1) {
    float* o = Out + ((size_t)b * L + l) * XR;
#pragma unroll
    for (int i = 0; i < 16; i += 4) {
      if (n0 + i + 4 <= XR)
        *(float4*)(o + n0 + i) = make_float4(acc[i], acc[i + 1], acc[i + 2], acc[i + 3]);
    }
    if (DODT && n0 == 0) {
      for (int d = 0; d < DH; ++d) {
        const float* wd = Wdt + d * DTR;
        float s = 2.f * bdt[d];
#pragma unroll
        for (int r = 0; r < DTR; ++r) s = fmaf(wd[r], acc[r], s);
        float v = (s > 20.f) ? s : __logf(1.f + __expf(s));
        dlt[((size_t)b * DH + d) * L + l] = v;
      }
    }
  } else {
    float* o = Out + ((size_t)b * N + n0) * L + lg;
#pragma unroll
    for (int i = 0; i < 16; ++i) o[(size_t)i * L] = acc[i];
  }
}

// ---------------------------------------------------------------------------
// causal depthwise conv (k=4) + SiLU, 4 l per thread (float4).
__global__ void k_conv_silu(const float* __restrict__ xz,
                            const float* __restrict__ cwx,
                            const float* __restrict__ cwz,
                            float* __restrict__ u,
                            float* __restrict__ ycat) {
  int idx = blockIdx.x * blockDim.x + threadIdx.x;
  const int per = NB * DH * (L / 4);
  int part = idx / per;
  int rem  = idx - part * per;
  int l4 = (rem & (L / 4 - 1)) * 4;
  int bd = rem >> 8;           // b*DH + d
  int d  = bd % DH;
  int b  = bd / DH;
  const float* cw = (part ? cwz : cwx) + d * 4;
  float w0 = cw[0], w1 = cw[1], w2 = cw[2], w3 = cw[3];
  const float* src = xz + ((size_t)b * DI + (part ? DH + d : d)) * L;
  float4 cur = *(const float4*)(src + l4);
  float pm3 = 0.f, pm2 = 0.f, pm1 = 0.f;
  if (l4 >= 4) {
    float4 p = *(const float4*)(src + l4 - 4);
    pm3 = p.y; pm2 = p.z; pm1 = p.w;
  }
  float s0 = fmaf(w3, cur.x, fmaf(w2, pm1,   fmaf(w1, pm2,   w0 * pm3)));
  float s1 = fmaf(w3, cur.y, fmaf(w2, cur.x, fmaf(w1, pm1,   w0 * pm2)));
  float s2 = fmaf(w3, cur.z, fmaf(w2, cur.y, fmaf(w1, cur.x, w0 * pm1)));
  float s3 = fmaf(w3, cur.w, fmaf(w2, cur.z, fmaf(w1, cur.y, w0 * cur.x)));
  float4 y;
  y.x = s0 / (1.f + __expf(-s0));
  y.y = s1 / (1.f + __expf(-s1));
  y.z = s2 / (1.f + __expf(-s2));
  y.w = s3 / (1.f + __expf(-s3));
  float* dst = part ? (ycat + ((size_t)b * DI + DH + d) * L + l4)
                    : (u + (size_t)bd * L + l4);
  *(float4*)dst = y;
}

// ---------------------------------------------------------------------------
// Chunked scan pass 1, 2 chains/wave sharing B loads. Lane l holds states
// {2l,2l+1} for chains d0 and d0+1. dt/du staged in LDS once per chunk.
__global__ void __launch_bounds__(256) k_scan1(const float* __restrict__ xdbl,
                                               const float* __restrict__ delta,
                                               const float* __restrict__ u,
                                               const float* __restrict__ Alog,
                                               float* __restrict__ hpart,
                                               float* __restrict__ apart) {
  __shared__ __align__(16) float dd[4][64][4];   // [wave][t][dt0,du0,dt1,du1]
  const int lane = threadIdx.x & 63;
  const int wv   = threadIdx.x >> 6;
  const int d0   = blockIdx.x * 8 + wv * 2;
  const int c = blockIdx.y, b = blockIdx.z;
  const int bd0 = b * DH + d0, bd1 = bd0 + 1;
  float2 Af0 = *(const float2*)(Alog + (size_t)d0 * DS + 2 * lane);
  float2 Af1 = *(const float2*)(Alog + (size_t)(d0 + 1) * DS + 2 * lane);
  const float a00 = -__expf(Af0.x) * LOG2E, a01 = -__expf(Af0.y) * LOG2E;
  const float a10 = -__expf(Af1.x) * LOG2E, a11 = -__expf(Af1.y) * LOG2E;
  const float* xrow  = xdbl + ((size_t)b * L + c * CL) * XR + DTR + 2 * lane;
  const float* drow0 = delta + (size_t)bd0 * L + c * CL;
  const float* drow1 = delta + (size_t)bd1 * L + c * CL;
  const float* urow0 = u + (size_t)bd0 * L + c * CL;
  const float* urow1 = u + (size_t)bd1 * L + c * CL;
  {
    float dt0 = drow0[lane], u0 = urow0[lane];
    float dt1 = drow1[lane], u1 = urow1[lane];
    *(float4*)&dd[wv][lane][0] = make_float4(dt0, dt0 * u0, dt1, dt1 * u1);
  }
  wave_lds_sync();
  float h00 = 0.f, h01 = 0.f, h10 = 0.f, h11 = 0.f;
  float p00 = 1.f, p01 = 1.f, p10 = 1.f, p11 = 1.f;
#pragma unroll 8
  for (int t = 0; t < CL; ++t) {
    float4 ddv = *(const float4*)&dd[wv][t][0];
    float2 Bv  = *(const float2*)(xrow + (size_t)t * XR);
    float e00 = __builtin_amdgcn_exp2f(ddv.x * a00);
    float e01 = __builtin_amdgcn_exp2f(ddv.x * a01);
    float e10 = __builtin_amdgcn_exp2f(ddv.z * a10);
    float e11 = __builtin_amdgcn_exp2f(ddv.z * a11);
    h00 = fmaf(e00, h00, ddv.y * Bv.x);
    h01 = fmaf(e01, h01, ddv.y * Bv.y);
    h10 = fmaf(e10, h10, ddv.w * Bv.x);
    h11 = fmaf(e11, h11, ddv.w * Bv.y);
    p00 *= e00; p01 *= e01; p10 *= e10; p11 *= e11;
  }
  *(float2*)(hpart + ((size_t)bd0 * NC + c) * 128 + 2 * lane) = make_float2(h00, h01);
  *(float2*)(hpart + ((size_t)bd1 * NC + c) * 128 + 2 * lane) = make_float2(h10, h11);
  *(float2*)(apart + ((size_t)bd0 * NC + c) * 128 + 2 * lane) = make_float2(p00, p01);
  *(float2*)(apart + ((size_t)bd1 * NC + c) * 128 + 2 * lane) = make_float2(p10, p11);
}

// ---------------------------------------------------------------------------
// pass 2: serial combine; overwrites hpart with true incoming state per chunk.
__global__ void __launch_bounds__(64) k_scan2(float* __restrict__ hpart,
                                              const float* __restrict__ apart) {
  const int bd   = blockIdx.x;
  const int lane = threadIdx.x;
  float H1 = 0.f, H2 = 0.f;
  size_t base = (size_t)bd * (NC * 128) + lane;
  for (int c = 0; c < NC; ++c) {
    size_t o = base + c * 128;
    float hp1 = hpart[o], hp2 = hpart[o + 64];
    float ap1 = apart[o], ap2 = apart[o + 64];
    hpart[o] = H1; hpart[o + 64] = H2;
    H1 = fmaf(ap1, H1, hp1);
    H2 = fmaf(ap2, H2, hp2);
  }
}

// ---------------------------------------------------------------------------
// pass 3: 2 chains/wave sharing B/C loads; LDS-staged dt/du; 8-step bursts
// with wave-synchronous transpose-reduce (no __syncthreads, no vmcnt drain).
__global__ void __launch_bounds__(256) k_scan3(const float* __restrict__ xdbl,
                                               const float* __restrict__ delta,
                                               const float* __restrict__ u,
                                               const float* __restrict__ Alog,
                                               const float* __restrict__ Dp,
                                               const float* __restrict__ hin,
                                               float* __restrict__ ycat) {
  __shared__ __align__(16) float dd[4][64][4];      // 4 KB
  __shared__ __align__(16) float pbuf[4][2][8][68]; // 17.4 KB
  const int lane = threadIdx.x & 63;
  const int wv   = threadIdx.x >> 6;
  const int d0   = blockIdx.x * 8 + wv * 2;
  const int c = blockIdx.y, b = blockIdx.z;
  const int bd0 = b * DH + d0, bd1 = bd0 + 1;
  float2 Af0 = *(const float2*)(Alog + (size_t)d0 * DS + 2 * lane);
  float2 Af1 = *(const float2*)(Alog + (size_t)(d0 + 1) * DS + 2 * lane);
  const float a00 = -__expf(Af0.x) * LOG2E, a01 = -__expf(Af0.y) * LOG2E;
  const float a10 = -__expf(Af1.x) * LOG2E, a11 = -__expf(Af1.y) * LOG2E;
  const float* xrow  = xdbl + ((size_t)b * L + c * CL) * XR + DTR + 2 * lane;
  const float* drow0 = delta + (size_t)bd0 * L + c * CL;
  const float* drow1 = delta + (size_t)bd1 * L + c * CL;
  const float* urow0 = u + (size_t)bd0 * L + c * CL;
  const float* urow1 = u + (size_t)bd1 * L + c * CL;
  {
    float dt0 = drow0[lane], u0 = urow0[lane];
    float dt1 = drow1[lane], u1 = urow1[lane];
    *(float4*)&dd[wv][lane][0] = make_float4(dt0, dt0 * u0, dt1, dt1 * u1);
  }
  wave_lds_sync();
  const float* hp0 = hin + ((size_t)bd0 * NC + c) * 128 + 2 * lane;
  const float* hp1 = hin + ((size_t)bd1 * NC + c) * 128 + 2 * lane;
  float2 h0 = *(const float2*)hp0;
  float2 h1 = *(const float2*)hp1;
  const int ch = lane >> 5, pp = (lane >> 3) & 3, tl = lane & 7;
  float* yrow_my = ycat + ((size_t)b * DI + d0 + ch) * L + c * CL;
  const float* urow_my = ch ? urow1 : urow0;
  const float Dd_my = Dp[d0 + ch];

  for (int t8 = 0; t8 < 8; ++t8) {
#pragma unroll
    for (int i = 0; i < 8; ++i) {
      const int t = t8 * 8 + i;
      float4 ddv = *(const float4*)&dd[wv][t][0];
      float2 Bv = *(const float2*)(xrow + (size_t)t * XR);
      float2 Cv = *(const float2*)(xrow + (size_t)t * XR + DS);
      float e00 = __builtin_amdgcn_exp2f(ddv.x * a00);
      float e01 = __builtin_amdgcn_exp2f(ddv.x * a01);
      float e10 = __builtin_amdgcn_exp2f(ddv.z * a10);
      float e11 = __builtin_amdgcn_exp2f(ddv.z * a11);
      h0.x = fmaf(e00, h0.x, ddv.y * Bv.x);
      h0.y = fmaf(e01, h0.y, ddv.y * Bv.y);
      h1.x = fmaf(e10, h1.x, ddv.w * Bv.x);
      h1.y = fmaf(e11, h1.y, ddv.w * Bv.y);
      pbuf[wv][0][i][lane] = fmaf(h0.y, Cv.y, h0.x * Cv.x);
      pbuf[wv][1][i][lane] = fmaf(h1.y, Cv.y, h1.x * Cv.x);
    }
    wave_lds_sync();                    // writes complete before transpose read
    const float* pr = &pbuf[wv][ch][tl][pp * 16];
    float4 v0 = *(const float4*)(pr);
    float4 v1 = *(const float4*)(pr + 4);
    float4 v2 = *(const float4*)(pr + 8);
    float4 v3 = *(const float4*)(pr + 12);
    float s = (((v0.x + v0.y) + (v0.z + v0.w)) + ((v1.x + v1.y) + (v1.z + v1.w)))
            + (((v2.x + v2.y) + (v2.z + v2.w)) + ((v3.x + v3.y) + (v3.z + v3.w)));
    s += __shfl_xor(s, 8, 64);
    s += __shfl_xor(s, 16, 64);
    if (pp == 0) {
      const int t = t8 * 8 + tl;
      yrow_my[t] = fmaf(Dd_my, urow_my[t], s);
    }
    __builtin_amdgcn_wave_barrier();    // reads ordered before next-burst writes
  }
}

// ---------------------------------------------------------------------------
// fallback serial scan, used only if ws too small.
__global__ void __launch_bounds__(64) k_scan(const float* __restrict__ xdbl,
                                             const float* __restrict__ delta,
                                             const float* __restrict__ u,
                                             const float* __restrict__ Alog,
                                             const float* __restrict__ Dp,
                                             float* __restrict__ ycat) {
  const int bd   = blockIdx.x;
  const int b    = bd / DH;
  const int d    = bd % DH;
  const int lane = threadIdx.x;
  const float a1 = -__expf(Alog[d * DS + lane]);
  const float a2 = -__expf(Alog[d * DS + 64 + lane]);
  const float* xrow = xdbl + (size_t)b * L * XR;
  const float* drow = delta + (size_t)bd * L;
  const float* urow = u + (size_t)bd * L;
  const float Dd = Dp[d];
  float* yrow = ycat + ((size_t)b * DI + d) * L;
  float h1 = 0.f, h2 = 0.f;
  for (int t = 0; t < L; ++t) {
    const float* xd = xrow + (size_t)t * XR;
    float Bv1 = xd[DTR + lane];
    float Bv2 = xd[DTR + 64 + lane];
    float Cv1 = xd[DTR + DS + lane];
    float Cv2 = xd[DTR + DS + 64 + lane];
    float dt = drow[t];
    float ut = urow[t];
    float du = dt * ut;
    h1 = fmaf(__expf(dt * a1), h1, du * Bv1);
    h2 = fmaf(__expf(dt * a2), h2, du * Bv2);
    float p = fmaf(h2, Cv2, h1 * Cv1);
#pragma unroll
    for (int m = 32; m; m >>= 1) p += __shfl_xor(p, m, 64);
    if (lane == 0) yrow[t] = fmaf(Dd, ut, p);
  }
}

// ---------------------------------------------------------------------------
extern "C" void kernel_launch(void* const* d_in, const int* in_sizes, int n_in,
                              void* d_out, int out_size, void* d_ws, size_t ws_size,
                              hipStream_t stream) {
  const float* hid  = (const float*)d_in[0];
  const float* Win  = (const float*)d_in[1];
  const float* cwx  = (const float*)d_in[2];
  const float* cwz  = (const float*)d_in[3];
  const float* Wx   = (const float*)d_in[4];
  const float* Wdt  = (const float*)d_in[5];
  const float* bdt  = (const float*)d_in[6];
  const float* Alog = (const float*)d_in[7];
  const float* Dp   = (const float*)d_in[8];
  const float* Wout = (const float*)d_in[9];
  float* out = (float*)d_out;

  float* ws    = (float*)d_ws;
  float* xz    = ws;                          // NB*DI*L   = 3,145,728
  float* u     = xz   + (size_t)NB * DI * L;  // NB*DH*L   = 1,572,864
  float* ycat  = u    + (size_t)NB * DH * L;  // NB*DI*L   = 3,145,728
  float* xdbl  = ycat + (size_t)NB * DI * L;  // NB*L*XR   = 2,195,456
  float* delta = xdbl + (size_t)NB * L * XR;  // NB*DH*L   = 1,572,864
  float* apart = delta + (size_t)NB * DH * L; // NB*DH*NC*128 = 3,145,728
  float* wt_in = apart + (size_t)NB * DH * NC * 128;  // 192*384 = 73,728
  float* wt_x  = wt_in + (size_t)192 * 384;           // 192*320 = 61,440
  float* wt_out= wt_x  + (size_t)192 * NWX;           // 384*192 = 73,728
  float* hpart = xz;                          // aliases xz (dead after conv)

  const size_t need = ((size_t)NB * DI * L * 2 + (size_t)NB * DH * L * 2 +
                       (size_t)NB * L * XR + (size_t)NB * DH * NC * 128 +
                       (size_t)192 * 384 + (size_t)192 * NWX + (size_t)384 * 192) * 4;

  k_wt_all<<<dim3(2, 384, 3), dim3(256), 0, stream>>>(Win, Wx, Wout, wt_in, wt_x, wt_out);

  k_gemm<192, 384, 384, 1, 0, 0><<<dim3(16, 6, NB), dim3(256), 0, stream>>>(
      hid, wt_in, xz, nullptr, nullptr, nullptr);
  k_conv_silu<<<dim3(2 * NB * DH * (L / 4) / 256), dim3(256), 0, stream>>>(xz, cwx, cwz, u, ycat);
  // xproj GEMM + fused delta epilogue
  k_gemm<192, XR, NWX, 0, 1, 1><<<dim3(16, 5, NB), dim3(256), 0, stream>>>(
      u, wt_x, xdbl, Wdt, bdt, delta);

  if (ws_size >= need) {
    k_scan1<<<dim3(DH / 8, NC, NB), dim3(256), 0, stream>>>(xdbl, delta, u, Alog, hpart, apart);
    k_scan2<<<dim3(NB * DH), dim3(64), 0, stream>>>(hpart, apart);
    k_scan3<<<dim3(DH / 8, NC, NB), dim3(256), 0, stream>>>(xdbl, delta, u, Alog, Dp, hpart, ycat);
  } else {
    k_scan<<<dim3(NB * DH), dim3(64), 0, stream>>>(xdbl, delta, u, Alog, Dp, ycat);
  }

  k_gemm<384, 192, 192, 0, 2, 0><<<dim3(16, 3, NB), dim3(256), 0, stream>>>(
      ycat, wt_out, out, nullptr, nullptr, nullptr);
}